// Round 2
// baseline (500.060 us; speedup 1.0000x reference)
//
#include <hip/hip_runtime.h>
#include <hip/hip_bf16.h>
#include <stdint.h>

#define T_    16
#define N_    32
#define C_    128
#define HW_   1024
#define COUT_ 128

typedef __bf16 bf16x8 __attribute__((ext_vector_type(8)));
typedef float  f32x4  __attribute__((ext_vector_type(4)));

// ---------------- K0: prep pw weights (bf16) + BN epilogue constants ----------------
__global__ __launch_bounds__(256) void k0_prep(
    const float* __restrict__ pw_w, const float* __restrict__ pw_b,
    const float* __restrict__ gamma, const float* __restrict__ beta,
    const float* __restrict__ mean,  const float* __restrict__ var,
    __bf16* __restrict__ wbf, float* __restrict__ scale2, float* __restrict__ bias2) {
  int idx = blockIdx.x * 256 + threadIdx.x;
  if (idx < COUT_ * C_) wbf[idx] = (__bf16)pw_w[idx];
  if (idx < COUT_) {
    float s = gamma[idx] * rsqrtf(var[idx] + 1e-5f);
    scale2[idx] = s;
    bias2[idx]  = beta[idx] + (pw_b[idx] - mean[idx]) * s;
  }
}

// ---------------- K1: LIF scan -> packed spike bits (float4 loads + bit-interleave) ----
// block = one (n,c). thread t owns px 4t..4t+3 (one float4 per timestep).
// S word layout identical to before: word[(nc*16+t)*32 + row] bit col = spike(row,col).
__global__ __launch_bounds__(256) void k1_lif(const float* __restrict__ x,
                                              uint32_t* __restrict__ S) {
  const int nc   = blockIdx.x;
  const int tid  = threadIdx.x;
  const int lane = tid & 63;
  const int wv   = tid >> 6;          // wave covers px [wv*256, wv*256+256) = rows [8wv, 8wv+8)
  const size_t base = (size_t)nc * HW_ + 4 * tid;

  f32x4 v = {0.f, 0.f, 0.f, 0.f};
#pragma unroll
  for (int t = 0; t < T_; ++t) {
    const f32x4 xv = *(const f32x4*)(x + (size_t)t * (N_ * C_ * HW_) + base);
    v = v + (xv - v) * 0.5f;
    bool s0 = (v.x >= 1.0f); if (s0) v.x = 0.f;
    bool s1 = (v.y >= 1.0f); if (s1) v.y = 0.f;
    bool s2 = (v.z >= 1.0f); if (s2) v.z = 0.f;
    bool s3 = (v.w >= 1.0f); if (s3) v.w = 0.f;
    unsigned long long m0 = __ballot(s0);   // bit i = spike at px wv*256 + 4i + 0
    unsigned long long m1 = __ballot(s1);
    unsigned long long m2 = __ballot(s2);
    unsigned long long m3 = __ballot(s3);
    if (lane < 8) {
      // lane q assembles row word q of this wave's 8 rows:
      // word bit 4j+b = m_b bit (8q + j)
      uint32_t wrd = 0;
      unsigned long long mm[4] = {m0, m1, m2, m3};
#pragma unroll
      for (int b = 0; b < 4; ++b) {
        uint32_t by = (uint32_t)(mm[b] >> (lane * 8)) & 0xFFu;
        by = (by | (by << 12)) & 0x000F000Fu;
        by = (by | (by << 6))  & 0x03030303u;
        by = (by | (by << 3))  & 0x11111111u;   // bit j -> bit 4j
        wrd |= by << b;
      }
      S[((size_t)nc * T_ + t) * 32 + wv * 8 + lane] = wrd;
    }
  }
}

// ---------------- K2: bits -> depthwise (VALU) -> MFMA GEMM -> BN -> staged stores ----
__global__ __launch_bounds__(256) void k2_main(
    const uint32_t* __restrict__ S,
    const float* __restrict__ dww, const float* __restrict__ dwb,
    const __bf16* __restrict__ wbf,
    const float* __restrict__ scale2, const float* __restrict__ bias2,
    float* __restrict__ out) {
  __shared__ __align__(16) unsigned char smem_u[34816];  // Blds (34816B) / f32 stage (33792B) union
  __shared__ uint32_t sb[C_ * 8];                        // [c][8]: rows r0-1 .. r0+4 (6 used)
  __bf16* Blds  = (__bf16*)smem_u;                       // [hw 0..127][c], pitch 136
  float*  stage = (float*)smem_u;                        // [o_local 0..63][hw 0..127], pitch 132

  const int bid   = blockIdx.x;
  const int n_img = bid >> 3;              // t*N + n
  const int rg    = bid & 7;
  const int t_img = n_img >> 5;
  const int n_in  = n_img & 31;
  const int r0    = rg * 4;
  const int tid   = threadIdx.x;

  // ---- Phase A: stage 128c x 6 spike row-words into LDS ----
#pragma unroll
  for (int k = 0; k < 3; ++k) {
    int li = k * 256 + tid;                // 0..767 = c*6 + ri
    int c  = li / 6;
    int ri = li - c * 6;
    int gr = r0 - 1 + ri;
    uint32_t wvv = 0;
    if (gr >= 0 && gr < 32)
      wvv = S[(((size_t)n_in * C_ + c) * T_ + t_img) * 32 + gr];
    sb[c * 8 + ri] = wvv;
  }
  __syncthreads();

  // ---- Phase B: depthwise 3x3 from bits -> bf16 B tile [hw][c] ----
  {
    int c    = tid & 127;
    int half = tid >> 7;                    // wave-uniform
    float w9[9];
#pragma unroll
    for (int i = 0; i < 9; ++i) w9[i] = dww[c * 9 + i];
    float bias = dwb[c];
    uint64_t R[6];
#pragma unroll
    for (int q = 0; q < 6; ++q) R[q] = ((uint64_t)sb[c * 8 + q]) << 1;

    int col0 = half * 16;
#pragma unroll 4
    for (int ci = 0; ci < 16; ++ci) {
      int col = col0 + ci;
      float acc[4] = {bias, bias, bias, bias};
#pragma unroll
      for (int q = 0; q < 6; ++q) {
        uint32_t tri = (uint32_t)(R[q] >> col) & 7u;  // bits col-1,col,col+1
        float b0 = (float)(tri & 1u);
        float b1 = (float)((tri >> 1) & 1u);
        float b2 = (float)(tri >> 2);
#pragma unroll
        for (int kh = 0; kh < 3; ++kh) {
          int r = q - kh;
          if (r >= 0 && r < 4) {
            acc[r] += w9[kh * 3 + 0] * b0;
            acc[r] += w9[kh * 3 + 1] * b1;
            acc[r] += w9[kh * 3 + 2] * b2;
          }
        }
      }
#pragma unroll
      for (int r = 0; r < 4; ++r)
        Blds[(r * 32 + col) * 136 + c] = (__bf16)acc[r];
    }
  }
  __syncthreads();

  // ---- Phase C: GEMM, operands SWAPPED: A = hw tile, B = weights ----
  // D[m=hw][n=o]: lane holds 4 consecutive hw (regs) at fixed o (lane&15).
  const int lane  = tid & 63;
  const int wid   = tid >> 6;
  const int ohalf = wid >> 1;
  const int hhalf = wid & 1;
  const int m16   = lane & 15;
  const int q4    = lane >> 4;

  // BN constants per n-tile (o = ohalf*64 + nt*16 + m16) — uniform across acc regs
  float sc_r[4], bs_r[4];
#pragma unroll
  for (int nt = 0; nt < 4; ++nt) {
    int o = ohalf * 64 + nt * 16 + m16;
    sc_r[nt] = scale2[o];
    bs_r[nt] = bias2[o];
  }

  f32x4 acc[4][4];
#pragma unroll
  for (int mt = 0; mt < 4; ++mt)
#pragma unroll
    for (int nt = 0; nt < 4; ++nt)
      acc[mt][nt] = (f32x4){0.f, 0.f, 0.f, 0.f};

#pragma unroll
  for (int ks = 0; ks < 4; ++ks) {
    const int k0 = ks * 32 + q4 * 8;
    bf16x8 hwf[4], of[4];
#pragma unroll
    for (int mt = 0; mt < 4; ++mt) {
      int hw = hhalf * 64 + mt * 16 + m16;
      hwf[mt] = *(const bf16x8*)(Blds + hw * 136 + k0);
    }
#pragma unroll
    for (int nt = 0; nt < 4; ++nt) {
      int o = ohalf * 64 + nt * 16 + m16;
      of[nt] = *(const bf16x8*)(wbf + o * 128 + k0);
    }
#pragma unroll
    for (int nt = 0; nt < 4; ++nt)
#pragma unroll
      for (int mt = 0; mt < 4; ++mt)
        acc[mt][nt] = __builtin_amdgcn_mfma_f32_16x16x32_bf16(hwf[mt], of[nt], acc[mt][nt], 0, 0, 0);
  }

  // ---- Epilogue: two o-halves through LDS stage, fully coalesced dwordx4 stores ----
  const size_t out_img = (size_t)n_img * (COUT_ * HW_) + (size_t)rg * 128;
#pragma unroll
  for (int h = 0; h < 2; ++h) {
    __syncthreads();
    if (ohalf == h) {
#pragma unroll
      for (int nt = 0; nt < 4; ++nt) {
        int olocal = nt * 16 + m16;
#pragma unroll
        for (int mt = 0; mt < 4; ++mt) {
          int hwl = hhalf * 64 + mt * 16 + q4 * 4;
          f32x4 vv = acc[mt][nt] * sc_r[nt] + bs_r[nt];
          *(f32x4*)(stage + olocal * 132 + hwl) = vv;
        }
      }
    }
    __syncthreads();
    // drain: 64 o-rows x 128 hw, 512B contiguous per o-row
#pragma unroll
    for (int i = 0; i < 8; ++i) {
      int idx    = i * 256 + tid;          // 0..2047
      int olocal = idx >> 5;
      int col    = idx & 31;
      f32x4 vv = *(const f32x4*)(stage + olocal * 132 + col * 4);
      *(f32x4*)(out + out_img + (size_t)(h * 64 + olocal) * HW_ + col * 4) = vv;
    }
  }
}

// ---------------- launcher ----------------
extern "C" void kernel_launch(void* const* d_in, const int* in_sizes, int n_in_args,
                              void* d_out, int out_size, void* d_ws, size_t ws_size,
                              hipStream_t stream) {
  const float* x     = (const float*)d_in[0];
  const float* dw_w  = (const float*)d_in[1];
  const float* dw_b  = (const float*)d_in[2];
  const float* pw_w  = (const float*)d_in[3];
  const float* pw_b  = (const float*)d_in[4];
  const float* gamma = (const float*)d_in[5];
  const float* beta  = (const float*)d_in[6];
  const float* rmean = (const float*)d_in[7];
  const float* rvar  = (const float*)d_in[8];
  float* out = (float*)d_out;

  uint32_t* S    = (uint32_t*)d_ws;
  __bf16* wbf    = (__bf16*)((char*)d_ws + (size_t)N_ * C_ * T_ * 128);
  float* scale2  = (float*)((char*)wbf + (size_t)COUT_ * C_ * 2);
  float* bias2   = scale2 + COUT_;

  k0_prep<<<64, 256, 0, stream>>>(pw_w, pw_b, gamma, beta, rmean, rvar, wbf, scale2, bias2);
  k1_lif<<<N_ * C_, 256, 0, stream>>>(x, S);
  k2_main<<<(T_ * N_) * 8, 256, 0, stream>>>(S, dw_w, dw_b, wbf, scale2, bias2, out);
}